// Round 1
// baseline (345.872 us; speedup 1.0000x reference)
//
#include <hip/hip_runtime.h>

// KDE entropy loss, MI355X/gfx950.
// ws layout: [0, 8 MiB) Xn bf16 [16384][256]; [8 MiB, +64 KiB) density f32 [16384].

#define NROWS 16384
#define KDIM 256
#define TM 128          // rows per block
#define TCCHUNK 2048    // cols per block strip
#define CT_ITERS (TCCHUNK / 128)

typedef __bf16 bf16x8 __attribute__((ext_vector_type(8)));
typedef float f32x4 __attribute__((ext_vector_type(4)));
typedef __attribute__((address_space(1))) const void global_cvoid_t;
typedef __attribute__((address_space(3))) void lds_void_t;

__device__ __forceinline__ unsigned short f2bf(float f) {
  unsigned int u = __float_as_uint(f);
  u += 0x7fffu + ((u >> 16) & 1u);   // round-to-nearest-even
  return (unsigned short)(u >> 16);
}

// One wave per row: compute 1/max(||x||,eps), write bf16; also zero density.
__global__ __launch_bounds__(256)
void kde_normalize(const float* __restrict__ X, unsigned short* __restrict__ Xn,
                   float* __restrict__ density) {
  const int wave = threadIdx.x >> 6;
  const int lane = threadIdx.x & 63;
  const int row = blockIdx.x * 4 + wave;
  const float4 v = ((const float4*)(X + (size_t)row * KDIM))[lane];
  float ss = v.x * v.x + v.y * v.y + v.z * v.z + v.w * v.w;
  ss += __shfl_xor(ss, 1);
  ss += __shfl_xor(ss, 2);
  ss += __shfl_xor(ss, 4);
  ss += __shfl_xor(ss, 8);
  ss += __shfl_xor(ss, 16);
  ss += __shfl_xor(ss, 32);
  const float scale = 1.0f / fmaxf(sqrtf(ss), 1e-12f);
  ushort4 o;
  o.x = f2bf(v.x * scale);
  o.y = f2bf(v.y * scale);
  o.z = f2bf(v.z * scale);
  o.w = f2bf(v.w * scale);
  ((ushort4*)(Xn + (size_t)row * KDIM))[lane] = o;
  if (threadIdx.x < 4) density[blockIdx.x * 4 + threadIdx.x] = 0.0f;
}

// Fused sim->exp->rowsum GEMM. Block: 256 threads (4 waves, 2x2 over a
// 128x128 C tile; each wave owns 64x64 = 4x4 MFMA tiles of 16x16x32 bf16).
// LDS (dynamic, 128 KB): As 64 KB (full K=256 of the block's 128 rows,
// fragment-ordered [rt(8)][kb(8)][lane(64)][16B]), Bs 64 KB (same layout
// for the current 128-col tile). Fragment-ordered layout makes both the
// global_load_lds staging (wave-uniform base + lane*16) and the
// ds_read_b128 fragment reads conflict-free.
__global__ __launch_bounds__(256)
void kde_gemm(const unsigned short* __restrict__ Xn, float* __restrict__ density) {
  extern __shared__ char smem[];
  char* As = smem;           // 64 KB
  char* Bs = smem + 65536;   // 64 KB

  const int tid = threadIdx.x;
  const int wave = tid >> 6;
  const int lane = tid & 63;
  const int wr = wave >> 1;  // wave row half (0..1)
  const int wc = wave & 1;   // wave col half (0..1)
  const int m = lane & 15;
  const int q = lane >> 4;
  const int row0 = blockIdx.x * TM;
  const int colbase0 = blockIdx.y * TCCHUNK;
  const char* Xb = (const char*)Xn;

  // Stage A tile (128 rows x full K) once. Chunk c=(rt*8+kb): lane holds
  // A[row0+rt*16+m][kb*32 + q*8 .. +7]  (matches MFMA A-operand layout).
  for (int c = wave; c < 64; c += 4) {
    const int rt = c >> 3, kb = c & 7;
    const size_t gofs = (size_t)(row0 + rt * 16 + m) * (KDIM * 2) + kb * 64 + q * 16;
    __builtin_amdgcn_global_load_lds((global_cvoid_t*)(Xb + gofs),
                                     (lds_void_t*)(As + c * 1024), 16, 0, 0);
  }

  float rs[4][4];  // [rt_local][reg] row-sum partials
#pragma unroll
  for (int i = 0; i < 4; i++)
#pragma unroll
    for (int r = 0; r < 4; r++) rs[i][r] = 0.0f;

  for (int ct = 0; ct < CT_ITERS; ++ct) {
    const int colbase = colbase0 + ct * 128;
    // Stage B tile (cols are rows of Xn: sim = Xn * Xn^T).
    for (int c = wave; c < 64; c += 4) {
      const int cs = c >> 3, kb = c & 7;
      const size_t gofs =
          (size_t)(colbase + cs * 16 + m) * (KDIM * 2) + kb * 64 + q * 16;
      __builtin_amdgcn_global_load_lds((global_cvoid_t*)(Xb + gofs),
                                       (lds_void_t*)(Bs + c * 1024), 16, 0, 0);
    }
    __syncthreads();  // drains vmcnt: A (first iter) + B staged

    f32x4 acc[4][4];
#pragma unroll
    for (int i = 0; i < 4; i++)
#pragma unroll
      for (int j = 0; j < 4; j++) acc[i][j] = (f32x4)0.0f;

#pragma unroll
    for (int kb = 0; kb < 8; ++kb) {
      bf16x8 af[4], bfr[4];
#pragma unroll
      for (int i = 0; i < 4; i++) {
        const int rt = wr * 4 + i;
        const int cs = wc * 4 + i;
        af[i] = *(const bf16x8*)(As + (rt * 8 + kb) * 1024 + lane * 16);
        bfr[i] = *(const bf16x8*)(Bs + (cs * 8 + kb) * 1024 + lane * 16);
      }
#pragma unroll
      for (int i = 0; i < 4; i++)
#pragma unroll
        for (int j = 0; j < 4; j++)
          acc[i][j] = __builtin_amdgcn_mfma_f32_16x16x32_bf16(af[i], bfr[j],
                                                              acc[i][j], 0, 0, 0);
    }

    // Fused epilogue: rowsum += exp(kappa * sim). C/D layout: col=lane&15,
    // row=(lane>>4)*4+reg -> row sum needs only (rt, reg) per lane.
#pragma unroll
    for (int i = 0; i < 4; i++)
#pragma unroll
      for (int j = 0; j < 4; j++)
#pragma unroll
        for (int r = 0; r < 4; r++) rs[i][r] += __expf(5.0f * acc[i][j][r]);

    __syncthreads();  // Bs consumed; safe to restage next iter
  }

  // Reduce across the 16 lanes sharing a row group, then atomics.
#pragma unroll
  for (int i = 0; i < 4; i++)
#pragma unroll
    for (int r = 0; r < 4; r++) {
      float v = rs[i][r];
      v += __shfl_xor(v, 1);
      v += __shfl_xor(v, 2);
      v += __shfl_xor(v, 4);
      v += __shfl_xor(v, 8);
      if ((lane & 15) == 0) {
        const int row = row0 + wr * 64 + i * 16 + q * 4 + r;
        atomicAdd(&density[row], v);
      }
    }
}

__global__ __launch_bounds__(256)
void kde_reduce(const float* __restrict__ density, float* __restrict__ out) {
  __shared__ float sdata[256];
  float s = 0.0f;
  for (int i = threadIdx.x; i < NROWS; i += 256) s += logf(density[i] + 1e-9f);
  sdata[threadIdx.x] = s;
  __syncthreads();
  for (int st = 128; st > 0; st >>= 1) {
    if (threadIdx.x < st) sdata[threadIdx.x] += sdata[threadIdx.x + st];
    __syncthreads();
  }
  if (threadIdx.x == 0) out[0] = -sdata[0] / (float)NROWS;
}

extern "C" void kernel_launch(void* const* d_in, const int* in_sizes, int n_in,
                              void* d_out, int out_size, void* d_ws, size_t ws_size,
                              hipStream_t stream) {
  const float* X = (const float*)d_in[0];
  float* out = (float*)d_out;
  char* ws = (char*)d_ws;
  unsigned short* Xn = (unsigned short*)ws;
  float* density = (float*)(ws + (size_t)NROWS * KDIM * 2);

  hipFuncSetAttribute((const void*)kde_gemm,
                      hipFuncAttributeMaxDynamicSharedMemorySize, 131072);

  kde_normalize<<<NROWS / 4, 256, 0, stream>>>(X, Xn, density);
  kde_gemm<<<dim3(NROWS / TM, NROWS / TCCHUNK), 256, 131072, stream>>>(Xn, density);
  kde_reduce<<<1, 256, 0, stream>>>(density, out);
}

// Round 2
// 167.232 us; speedup vs baseline: 2.0682x; 2.0682x over previous
//
#include <hip/hip_runtime.h>

// KDE entropy loss, MI355X/gfx950 — fp8-MX (e4m3, scale=1) fused GEMM.
// ws layout: [0, 4 MiB) Xn fp8 [16384][256]; [4 MiB, +64 KiB) density f32 [16384].

#define NROWS 16384
#define KDIM 256            // bytes per fp8 row
#define TM 128              // rows per block
#define TCCHUNK 2048        // cols per block strip
#define CT_ITERS (TCCHUNK / 128)

typedef int i32x4_t __attribute__((ext_vector_type(4)));
typedef int i32x8_t __attribute__((ext_vector_type(8)));
typedef float f32x16_t __attribute__((ext_vector_type(16)));
typedef __attribute__((address_space(1))) const void global_cvoid_t;
typedef __attribute__((address_space(3))) void lds_void_t;

// One wave per row: 1/max(||x||,eps), write fp8 e4m3 (HW cvt, RNE); zero density.
__global__ __launch_bounds__(256)
void kde_normalize(const float* __restrict__ X, unsigned int* __restrict__ Xn8,
                   float* __restrict__ density) {
  const int wave = threadIdx.x >> 6;
  const int lane = threadIdx.x & 63;
  const int row = blockIdx.x * 4 + wave;
  const float4 v = ((const float4*)(X + (size_t)row * KDIM))[lane];
  float ss = v.x * v.x + v.y * v.y + v.z * v.z + v.w * v.w;
  ss += __shfl_xor(ss, 1);
  ss += __shfl_xor(ss, 2);
  ss += __shfl_xor(ss, 4);
  ss += __shfl_xor(ss, 8);
  ss += __shfl_xor(ss, 16);
  ss += __shfl_xor(ss, 32);
  const float scale = 1.0f / fmaxf(sqrtf(ss), 1e-12f);
  int p = 0;
  p = __builtin_amdgcn_cvt_pk_fp8_f32(v.x * scale, v.y * scale, p, false);
  p = __builtin_amdgcn_cvt_pk_fp8_f32(v.z * scale, v.w * scale, p, true);
  Xn8[(size_t)row * 64 + lane] = (unsigned int)p;
  if (threadIdx.x < 4) density[blockIdx.x * 4 + threadIdx.x] = 0.0f;
}

// Fused sim->exp->rowsum GEMM, fp8 MX path. Block: 256 threads, 4 waves 2x2
// over a 128x128 C tile; each wave 64x64 = 2x2 MFMA tiles of 32x32x64 fp8
// (scales = 1.0 -> exact e4m3 matmul). LDS 64 KB total (As 32 + Bs 32) ->
// 2 blocks/CU. Layout: 1 KB chunks [lane][16B]; fragment (t,kb) = 2 chunks
// (k-bytes 0-15, 16-31 of each lane's 32). Staging for next ct is issued
// BEFORE the exp epilogue so its latency hides under the v_exp_f32 work.
__global__ __launch_bounds__(256, 2)
void kde_gemm(const unsigned char* __restrict__ Xn8, float* __restrict__ density) {
  extern __shared__ char smem[];
  char* As = smem;           // 32 KB
  char* Bs = smem + 32768;   // 32 KB

  const int tid = threadIdx.x;
  const int wave = tid >> 6;
  const int lane = tid & 63;
  const int wr = wave >> 1;   // wave row half
  const int wc = wave & 1;    // wave col half
  const int m32 = lane & 31;
  const int h = lane >> 5;    // k-half within fragment
  const int row0 = blockIdx.x * TM;
  const int colbase0 = blockIdx.y * TCCHUNK;
  const char* Xb = (const char*)Xn8;

  // Stage A (128 rows x 256 B) once. Chunk c = rt*8 + kb*2 + hh:
  // lane holds A[row0+rt*32+m32][kb*64 + h*32 + hh*16 .. +15].
  for (int c = wave; c < 32; c += 4) {
    const int rt = c >> 3, kb = (c >> 1) & 3, hh = c & 1;
    const size_t gofs = (size_t)(row0 + rt * 32 + m32) * KDIM + kb * 64 + h * 32 + hh * 16;
    __builtin_amdgcn_global_load_lds((global_cvoid_t*)(Xb + gofs),
                                     (lds_void_t*)(As + c * 1024), 16, 0, 0);
  }

#define STAGE_B(colbase)                                                          \
  for (int c = wave; c < 32; c += 4) {                                            \
    const int cs = c >> 3, kb = (c >> 1) & 3, hh = c & 1;                         \
    const size_t gofs =                                                           \
        (size_t)((colbase) + cs * 32 + m32) * KDIM + kb * 64 + h * 32 + hh * 16;  \
    __builtin_amdgcn_global_load_lds((global_cvoid_t*)(Xb + gofs),                \
                                     (lds_void_t*)(Bs + c * 1024), 16, 0, 0);     \
  }

  float rs[2][16];  // [row-tile][reg] row-sum partials
#pragma unroll
  for (int i = 0; i < 2; i++)
#pragma unroll
    for (int r = 0; r < 16; r++) rs[i][r] = 0.0f;

  STAGE_B(colbase0);

  for (int ct = 0; ct < CT_ITERS; ++ct) {
    __syncthreads();  // B(ct) landed (compiler drains vmcnt before barrier)

    f32x16_t acc[2][2];
#pragma unroll
    for (int i = 0; i < 2; i++)
#pragma unroll
      for (int j = 0; j < 2; j++) acc[i][j] = (f32x16_t)0.0f;

#pragma unroll
    for (int kb = 0; kb < 4; ++kb) {
      i32x8_t af[2], bfr[2];
#pragma unroll
      for (int i = 0; i < 2; i++) {
        const char* pa = As + ((wr * 2 + i) * 8 + kb * 2) * 1024 + lane * 16;
        i32x4_t alo = *(const i32x4_t*)pa;
        i32x4_t ahi = *(const i32x4_t*)(pa + 1024);
        af[i][0] = alo[0]; af[i][1] = alo[1]; af[i][2] = alo[2]; af[i][3] = alo[3];
        af[i][4] = ahi[0]; af[i][5] = ahi[1]; af[i][6] = ahi[2]; af[i][7] = ahi[3];
        const char* pb = Bs + ((wc * 2 + i) * 8 + kb * 2) * 1024 + lane * 16;
        i32x4_t blo = *(const i32x4_t*)pb;
        i32x4_t bhi = *(const i32x4_t*)(pb + 1024);
        bfr[i][0] = blo[0]; bfr[i][1] = blo[1]; bfr[i][2] = blo[2]; bfr[i][3] = blo[3];
        bfr[i][4] = bhi[0]; bfr[i][5] = bhi[1]; bfr[i][6] = bhi[2]; bfr[i][7] = bhi[3];
      }
#pragma unroll
      for (int i = 0; i < 2; i++)
#pragma unroll
        for (int j = 0; j < 2; j++)
          acc[i][j] = __builtin_amdgcn_mfma_scale_f32_32x32x64_f8f6f4(
              af[i], bfr[j], acc[i][j], 0, 0, 0, 127, 0, 127);
    }

    __syncthreads();  // all waves done reading Bs (cheap: no vmem outstanding)

    if (ct + 1 < CT_ITERS) {
      const int colbase = colbase0 + (ct + 1) * 128;
      STAGE_B(colbase);  // fire-and-forget; latency hidden by epilogue below
    }

    // Fused epilogue: rowsum += exp(kappa*sim). C/D 32x32 layout:
    // col = lane&31, row = (reg&3) + 8*(reg>>2) + 4*(lane>>5).
#pragma unroll
    for (int i = 0; i < 2; i++)
#pragma unroll
      for (int j = 0; j < 2; j++)
#pragma unroll
        for (int r = 0; r < 16; r++) rs[i][r] += __expf(5.0f * acc[i][j][r]);
  }

  // Reduce across the 32 lanes sharing a row set, then atomics.
#pragma unroll
  for (int i = 0; i < 2; i++)
#pragma unroll
    for (int r = 0; r < 16; r++) {
      float v = rs[i][r];
      v += __shfl_xor(v, 1);
      v += __shfl_xor(v, 2);
      v += __shfl_xor(v, 4);
      v += __shfl_xor(v, 8);
      v += __shfl_xor(v, 16);
      if (m32 == 0) {
        const int row = row0 + (wr * 2 + i) * 32 + (r & 3) + 8 * (r >> 2) + 4 * h;
        atomicAdd(&density[row], v);
      }
    }
#undef STAGE_B
}

__global__ __launch_bounds__(256)
void kde_reduce(const float* __restrict__ density, float* __restrict__ out) {
  __shared__ float sdata[256];
  float s = 0.0f;
  for (int i = threadIdx.x; i < NROWS; i += 256) s += logf(density[i] + 1e-9f);
  sdata[threadIdx.x] = s;
  __syncthreads();
  for (int st = 128; st > 0; st >>= 1) {
    if (threadIdx.x < st) sdata[threadIdx.x] += sdata[threadIdx.x + st];
    __syncthreads();
  }
  if (threadIdx.x == 0) out[0] = -sdata[0] / (float)NROWS;
}

extern "C" void kernel_launch(void* const* d_in, const int* in_sizes, int n_in,
                              void* d_out, int out_size, void* d_ws, size_t ws_size,
                              hipStream_t stream) {
  const float* X = (const float*)d_in[0];
  float* out = (float*)d_out;
  char* ws = (char*)d_ws;
  unsigned int* Xn8 = (unsigned int*)ws;
  float* density = (float*)(ws + (size_t)NROWS * KDIM);

  hipFuncSetAttribute((const void*)kde_gemm,
                      hipFuncAttributeMaxDynamicSharedMemorySize, 65536);

  kde_normalize<<<NROWS / 4, 256, 0, stream>>>(X, Xn8, density);
  kde_gemm<<<dim3(NROWS / TM, NROWS / TCCHUNK), 256, 65536, stream>>>(
      (const unsigned char*)ws, density);
  kde_reduce<<<1, 256, 0, stream>>>(density, out);
}

// Round 3
// 156.510 us; speedup vs baseline: 2.2099x; 1.0685x over previous
//
#include <hip/hip_runtime.h>

// KDE entropy loss, MI355X/gfx950 — fp8 MX fused GEMM, upper-triangle only.
// sim is symmetric: tile (I,J), J>=I computed once; rowsums -> density[I-rows],
// colsums -> density[J-rows] (skipped on diagonal tiles).
// ws: [0,4MiB) Xn fp8 [16384][256]; [4MiB,+64KiB) density f32; then partial[64].

#define NROWS 16384
#define KDIM 256            // bytes per fp8 row
#define NTILE 128           // tile edge
#define NT (NROWS / NTILE)  // 128 tile rows
#define STRIP 4             // J-tiles per block

typedef int i32x4_t __attribute__((ext_vector_type(4)));
typedef int i32x8_t __attribute__((ext_vector_type(8)));
typedef float f32x16_t __attribute__((ext_vector_type(16)));
typedef __attribute__((address_space(1))) const void global_cvoid_t;
typedef __attribute__((address_space(3))) void lds_void_t;

#if __has_builtin(__builtin_amdgcn_exp2f)
#define EXPK(x) __builtin_amdgcn_exp2f((x) * 7.2134752044448f)  // exp(5x)=2^(x*5*log2e)
#else
#define EXPK(x) __expf(5.0f * (x))
#endif

union frag8 { i32x8_t v8; i32x4_t v4[2]; };

// One wave per row: 1/max(||x||,eps), fp8 e4m3 out; zero density.
__global__ __launch_bounds__(256)
void kde_normalize(const float* __restrict__ X, unsigned int* __restrict__ Xn8,
                   float* __restrict__ density) {
  const int wave = threadIdx.x >> 6;
  const int lane = threadIdx.x & 63;
  const int row = blockIdx.x * 4 + wave;
  const float4 v = ((const float4*)(X + (size_t)row * KDIM))[lane];
  float ss = v.x * v.x + v.y * v.y + v.z * v.z + v.w * v.w;
  ss += __shfl_xor(ss, 1);
  ss += __shfl_xor(ss, 2);
  ss += __shfl_xor(ss, 4);
  ss += __shfl_xor(ss, 8);
  ss += __shfl_xor(ss, 16);
  ss += __shfl_xor(ss, 32);
  const float scale = 1.0f / fmaxf(sqrtf(ss), 1e-12f);
  int p = 0;
  p = __builtin_amdgcn_cvt_pk_fp8_f32(v.x * scale, v.y * scale, p, false);
  p = __builtin_amdgcn_cvt_pk_fp8_f32(v.z * scale, v.w * scale, p, true);
  Xn8[(size_t)row * 64 + lane] = (unsigned int)p;
  if (threadIdx.x < 4) density[blockIdx.x * 4 + threadIdx.x] = 0.0f;
}

// Block = (bi, s): row tile bi, J tiles s*4+ct for ct in [max(0,bi-s*4), 4).
// 4 waves 2x2 over the 128x128 tile; wave = 64x64 = 2x2 MFMA 32x32x64 fp8.
// LDS 64 KB (As 32 + Bs 32) -> 2 blocks/CU.
__global__ __launch_bounds__(256, 2)
void kde_gemm(const unsigned char* __restrict__ Xn8, float* __restrict__ density) {
  const int bi = blockIdx.x;
  const int s = blockIdx.y;
  int ct0 = bi - s * STRIP;
  if (ct0 >= STRIP) return;  // strip entirely below diagonal
  if (ct0 < 0) ct0 = 0;

  extern __shared__ char smem[];
  char* As = smem;           // 32 KB
  char* Bs = smem + 32768;   // 32 KB

  const int tid = threadIdx.x;
  const int wave = tid >> 6;
  const int lane = tid & 63;
  const int wr = wave >> 1;
  const int wc = wave & 1;
  const int m32 = lane & 31;
  const int h = lane >> 5;
  const char* Xb = (const char*)Xn8;

  // Stage A (rows bi*128..+128, full K). Chunk c = rt*8 + kb*2 + hh:
  // lane holds M[rt*32+m32][kb*64 + h*32 + hh*16 .. +15] (MFMA operand layout).
#define STAGE(base_row, dst)                                                      \
  for (int c = wave; c < 32; c += 4) {                                            \
    const int rt = c >> 3, kb = (c >> 1) & 3, hh = c & 1;                         \
    const size_t gofs =                                                           \
        (size_t)((base_row) + rt * 32 + m32) * KDIM + kb * 64 + h * 32 + hh * 16; \
    __builtin_amdgcn_global_load_lds((global_cvoid_t*)(Xb + gofs),                \
                                     (lds_void_t*)((dst) + c * 1024), 16, 0, 0);  \
  }

  STAGE(bi * NTILE, As);
  STAGE((s * STRIP + ct0) * NTILE, Bs);

  float rs[2][16];
#pragma unroll
  for (int i = 0; i < 2; i++)
#pragma unroll
    for (int r = 0; r < 16; r++) rs[i][r] = 0.0f;

  for (int ct = ct0; ct < STRIP; ++ct) {
    const int J = s * STRIP + ct;
    __syncthreads();  // A + B(ct) landed (compiler drains vmcnt before barrier)

    f32x16_t acc[2][2];
#pragma unroll
    for (int i = 0; i < 2; i++)
#pragma unroll
      for (int j = 0; j < 2; j++) acc[i][j] = (f32x16_t)0.0f;

#pragma unroll
    for (int kb = 0; kb < 4; ++kb) {
      frag8 af[2], bf[2];
#pragma unroll
      for (int i = 0; i < 2; i++) {
        const char* pa = As + ((wr * 2 + i) * 8 + kb * 2) * 1024 + lane * 16;
        af[i].v4[0] = *(const i32x4_t*)pa;
        af[i].v4[1] = *(const i32x4_t*)(pa + 1024);
        const char* pb = Bs + ((wc * 2 + i) * 8 + kb * 2) * 1024 + lane * 16;
        bf[i].v4[0] = *(const i32x4_t*)pb;
        bf[i].v4[1] = *(const i32x4_t*)(pb + 1024);
      }
#pragma unroll
      for (int i = 0; i < 2; i++)
#pragma unroll
        for (int j = 0; j < 2; j++)
          acc[i][j] = __builtin_amdgcn_mfma_scale_f32_32x32x64_f8f6f4(
              af[i].v8, bf[j].v8, acc[i][j], 0, 0, 0, 127, 0, 127);
    }

    __syncthreads();  // Bs consumed (cheap: no vmem outstanding)

    if (ct + 1 < STRIP) STAGE((J + 1) * NTILE, Bs);  // latency hides under epilogue

    // Epilogue: e = exp(5*sim) once; rowsums accumulate in regs across ct,
    // colsums reduced+scattered now. C/D: col=m32, row=(r&3)+8*(r>>2)+4*h.
    float cs[2] = {0.0f, 0.0f};
#pragma unroll
    for (int i = 0; i < 2; i++)
#pragma unroll
      for (int j = 0; j < 2; j++)
#pragma unroll
        for (int r = 0; r < 16; r++) {
          const float e = EXPK(acc[i][j][r]);
          rs[i][r] += e;
          cs[j] += e;
        }

    if (J != bi) {  // diagonal tile: rowsum only (no double count)
#pragma unroll
      for (int j = 0; j < 2; j++) {
        float v = cs[j] + __shfl_xor(cs[j], 32);  // combine row-halves h=0/1
        if (h == 0)  // 2 atomics per col (wr=0,1 waves) — partials over 64 rows
          atomicAdd(&density[J * NTILE + wc * 64 + j * 32 + m32], v);
      }
    }
  }

  // Row epilogue: reduce over 32 cols (m32) then scatter; 2 atomics/row (wc=0,1).
#pragma unroll
  for (int i = 0; i < 2; i++)
#pragma unroll
    for (int r = 0; r < 16; r++) {
      float v = rs[i][r];
      v += __shfl_xor(v, 1);
      v += __shfl_xor(v, 2);
      v += __shfl_xor(v, 4);
      v += __shfl_xor(v, 8);
      v += __shfl_xor(v, 16);
      if (m32 == 0) {
        const int row = bi * NTILE + wr * 64 + i * 32 + (r & 3) + 8 * (r >> 2) + 4 * h;
        atomicAdd(&density[row], v);
      }
    }
#undef STAGE
}

// Two-stage log reduce: 64 blocks x 256 (one element/thread) -> 64 partials -> 1.
__global__ __launch_bounds__(256)
void kde_logpart(const float* __restrict__ density, float* __restrict__ partial) {
  const int wave = threadIdx.x >> 6;
  const int lane = threadIdx.x & 63;
  float v = logf(density[blockIdx.x * 256 + threadIdx.x] + 1e-9f);
  v += __shfl_xor(v, 1);
  v += __shfl_xor(v, 2);
  v += __shfl_xor(v, 4);
  v += __shfl_xor(v, 8);
  v += __shfl_xor(v, 16);
  v += __shfl_xor(v, 32);
  __shared__ float w[4];
  if (lane == 0) w[wave] = v;
  __syncthreads();
  if (threadIdx.x == 0) partial[blockIdx.x] = w[0] + w[1] + w[2] + w[3];
}

__global__ __launch_bounds__(64)
void kde_final(const float* __restrict__ partial, float* __restrict__ out) {
  float v = partial[threadIdx.x];
  v += __shfl_xor(v, 1);
  v += __shfl_xor(v, 2);
  v += __shfl_xor(v, 4);
  v += __shfl_xor(v, 8);
  v += __shfl_xor(v, 16);
  v += __shfl_xor(v, 32);
  if (threadIdx.x == 0) out[0] = -v / (float)NROWS;
}

extern "C" void kernel_launch(void* const* d_in, const int* in_sizes, int n_in,
                              void* d_out, int out_size, void* d_ws, size_t ws_size,
                              hipStream_t stream) {
  const float* X = (const float*)d_in[0];
  float* out = (float*)d_out;
  char* ws = (char*)d_ws;
  unsigned int* Xn8 = (unsigned int*)ws;
  float* density = (float*)(ws + (size_t)NROWS * KDIM);
  float* partial = density + NROWS;

  hipFuncSetAttribute((const void*)kde_gemm,
                      hipFuncAttributeMaxDynamicSharedMemorySize, 65536);

  kde_normalize<<<NROWS / 4, 256, 0, stream>>>(X, Xn8, density);
  kde_gemm<<<dim3(NT, NT / STRIP), 256, 65536, stream>>>((const unsigned char*)ws,
                                                         density);
  kde_logpart<<<64, 256, 0, stream>>>(density, partial);
  kde_final<<<1, 64, 0, stream>>>(partial, out);
}

// Round 4
// 135.239 us; speedup vs baseline: 2.5575x; 1.1573x over previous
//
#include <hip/hip_runtime.h>

// KDE entropy loss, MI355X/gfx950 — fp8 fused GEMM, symmetric pairs once,
// wrapped-diagonal balanced mapping, ticketed in-kernel final reduction.
// ws: [0,4MiB) Xn fp8 [16384][256]; [4MiB,+64KiB) density f32; then ticket u32.

#define NROWS 16384
#define KDIM 256            // bytes per fp8 row
#define NTILE 128
#define NT (NROWS / NTILE)  // 128 tile rows
#define NSTRIP 4
#define TOTAL_BLOCKS (NT * NSTRIP)  // 512 = exactly 2 per CU

typedef int i32x4_t __attribute__((ext_vector_type(4)));
typedef int i32x8_t __attribute__((ext_vector_type(8)));
typedef float f32x16_t __attribute__((ext_vector_type(16)));
typedef __attribute__((address_space(1))) const void global_cvoid_t;
typedef __attribute__((address_space(3))) void lds_void_t;

#if __has_builtin(__builtin_amdgcn_exp2f)
#define EXPK(x) __builtin_amdgcn_exp2f((x) * 7.2134752044448f)  // exp(5x)=2^(x*5log2e)
#else
#define EXPK(x) __expf(5.0f * (x))
#endif

union frag8 { i32x8_t v8; i32x4_t v4[2]; };

// One wave per row: 1/max(||x||,eps), fp8 e4m3 out; zero density + ticket.
__global__ __launch_bounds__(256)
void kde_normalize(const float* __restrict__ X, unsigned int* __restrict__ Xn8,
                   float* __restrict__ density, unsigned int* __restrict__ ticket) {
  const int wave = threadIdx.x >> 6;
  const int lane = threadIdx.x & 63;
  const int row = blockIdx.x * 4 + wave;
  const float4 v = ((const float4*)(X + (size_t)row * KDIM))[lane];
  float ss = v.x * v.x + v.y * v.y + v.z * v.z + v.w * v.w;
  ss += __shfl_xor(ss, 1);
  ss += __shfl_xor(ss, 2);
  ss += __shfl_xor(ss, 4);
  ss += __shfl_xor(ss, 8);
  ss += __shfl_xor(ss, 16);
  ss += __shfl_xor(ss, 32);
  const float scale = 1.0f / fmaxf(sqrtf(ss), 1e-12f);
  int p = 0;
  p = __builtin_amdgcn_cvt_pk_fp8_f32(v.x * scale, v.y * scale, p, false);
  p = __builtin_amdgcn_cvt_pk_fp8_f32(v.z * scale, v.w * scale, p, true);
  Xn8[(size_t)row * 64 + lane] = (unsigned int)p;
  if (threadIdx.x < 4) density[blockIdx.x * 4 + threadIdx.x] = 0.0f;
  if (blockIdx.x == 0 && threadIdx.x == 0) *ticket = 0u;
}

// Block (bi, s): row tile bi; J-tiles (bi+t) mod 128 for t in [s*16, s*16+16)
// (+ t=64 for s=3, bi<64). Each unordered tile pair computed once; rowsums ->
// tile bi (registers, atomics at end), colsums -> tile J (atomics per tile,
// skipped for t=0 diagonal). 4 waves 2x2 over 128x128; wave = 2x2 MFMA
// 32x32x64 fp8 (scale=1 -> exact e4m3). LDS 64 KB -> 2 blocks/CU.
// Last block (device ticket) computes the entropy scalar in-kernel.
__global__ __launch_bounds__(256, 2)
void kde_gemm(const unsigned char* __restrict__ Xn8, float* __restrict__ density,
              unsigned int* __restrict__ ticket, float* __restrict__ out) {
  extern __shared__ char smem[];
  char* As = smem;           // 32 KB
  char* Bs = smem + 32768;   // 32 KB

  const int tid = threadIdx.x;
  const int wave = tid >> 6;
  const int lane = tid & 63;
  const int wr = wave >> 1;
  const int wc = wave & 1;
  const int m32 = lane & 31;
  const int h = lane >> 5;
  const int bi = blockIdx.x;
  const int s = blockIdx.y;
  const int t0 = s * 16;
  const int nt = (s == NSTRIP - 1 && bi < NT / 2) ? 17 : 16;
  const char* Xb = (const char*)Xn8;

  // Chunk c = rt*8 + kb*2 + hh: lane holds M[rt*32+m32][kb*64+h*32+hh*16 ..+15].
#define STAGE(base_row, dst)                                                      \
  for (int c = wave; c < 32; c += 4) {                                            \
    const int rt = c >> 3, kb = (c >> 1) & 3, hh = c & 1;                         \
    const size_t gofs =                                                           \
        (size_t)((base_row) + rt * 32 + m32) * KDIM + kb * 64 + h * 32 + hh * 16; \
    __builtin_amdgcn_global_load_lds((global_cvoid_t*)(Xb + gofs),                \
                                     (lds_void_t*)((dst) + c * 1024), 16, 0, 0);  \
  }

  STAGE(bi * NTILE, As);
  STAGE(((bi + t0) & (NT - 1)) * NTILE, Bs);

  float rs[2][16];
#pragma unroll
  for (int i = 0; i < 2; i++)
#pragma unroll
    for (int r = 0; r < 16; r++) rs[i][r] = 0.0f;

  for (int k = 0; k < nt; ++k) {
    const int t = t0 + k;
    const int J = (bi + t) & (NT - 1);
    __syncthreads();  // A + B(k) landed (compiler drains vmcnt before barrier)

    f32x16_t acc[2][2];
#pragma unroll
    for (int i = 0; i < 2; i++)
#pragma unroll
      for (int j = 0; j < 2; j++) acc[i][j] = (f32x16_t)0.0f;

#pragma unroll
    for (int kb = 0; kb < 4; ++kb) {
      frag8 af[2], bf[2];
#pragma unroll
      for (int i = 0; i < 2; i++) {
        const char* pa = As + ((wr * 2 + i) * 8 + kb * 2) * 1024 + lane * 16;
        af[i].v4[0] = *(const i32x4_t*)pa;
        af[i].v4[1] = *(const i32x4_t*)(pa + 1024);
        const char* pb = Bs + ((wc * 2 + i) * 8 + kb * 2) * 1024 + lane * 16;
        bf[i].v4[0] = *(const i32x4_t*)pb;
        bf[i].v4[1] = *(const i32x4_t*)(pb + 1024);
      }
#pragma unroll
      for (int i = 0; i < 2; i++)
#pragma unroll
        for (int j = 0; j < 2; j++)
          acc[i][j] = __builtin_amdgcn_mfma_scale_f32_32x32x64_f8f6f4(
              af[i].v8, bf[j].v8, acc[i][j], 0, 0, 0, 127, 0, 127);
    }

    __syncthreads();  // Bs consumed (cheap: no vmem outstanding)

    if (k + 1 < nt) STAGE(((J + 1) & (NT - 1)) * NTILE, Bs);  // hides under epilogue

    // Epilogue: e = exp(5*sim); rowsums in regs across k, colsums scattered now.
    // C/D: col = m32, row = (r&3) + 8*(r>>2) + 4*h.
    float cs[2] = {0.0f, 0.0f};
#pragma unroll
    for (int i = 0; i < 2; i++)
#pragma unroll
      for (int j = 0; j < 2; j++)
#pragma unroll
        for (int r = 0; r < 16; r++) {
          const float e = EXPK(acc[i][j][r]);
          rs[i][r] += e;
          cs[j] += e;
        }

    if (t != 0) {  // diagonal tile (t=0): rowsum only
#pragma unroll
      for (int j = 0; j < 2; j++) {
        float v = cs[j] + __shfl_xor(cs[j], 32);  // combine h halves -> 64 rows
        if (h == 0)  // 2 atomics/col (wr=0,1 waves)
          atomicAdd(&density[J * NTILE + wc * 64 + j * 32 + m32], v);
      }
    }
  }

  // Row epilogue: reduce over 32 cols (m32) then scatter; 2 atomics/row (wc).
#pragma unroll
  for (int i = 0; i < 2; i++)
#pragma unroll
    for (int r = 0; r < 16; r++) {
      float v = rs[i][r];
      v += __shfl_xor(v, 1);
      v += __shfl_xor(v, 2);
      v += __shfl_xor(v, 4);
      v += __shfl_xor(v, 8);
      v += __shfl_xor(v, 16);
      if (m32 == 0) {
        const int row = bi * NTILE + wr * 64 + i * 32 + (r & 3) + 8 * (r >> 2) + 4 * h;
        atomicAdd(&density[row], v);
      }
    }
#undef STAGE

  // Ticket: last finished block computes the entropy (saves 2 launches).
  __syncthreads();  // all waves' atomics issued & drained (vmcnt(0) at barrier)
  if (tid == 0) {
    __threadfence();
    ((volatile unsigned int*)smem)[0] = atomicAdd(ticket, 1u);
  }
  __syncthreads();
  if (((volatile unsigned int*)smem)[0] == TOTAL_BLOCKS - 1) {
    __threadfence();
    float ssum = 0.0f;
    for (int i = tid; i < NROWS; i += 256) {
      const float d = __hip_atomic_load(&density[i], __ATOMIC_RELAXED,
                                        __HIP_MEMORY_SCOPE_AGENT);
      ssum += logf(d + 1e-9f);
    }
    ssum += __shfl_xor(ssum, 1);
    ssum += __shfl_xor(ssum, 2);
    ssum += __shfl_xor(ssum, 4);
    ssum += __shfl_xor(ssum, 8);
    ssum += __shfl_xor(ssum, 16);
    ssum += __shfl_xor(ssum, 32);
    float* red = ((float*)smem) + 16;
    if (lane == 0) red[wave] = ssum;
    __syncthreads();
    if (tid == 0) out[0] = -(red[0] + red[1] + red[2] + red[3]) / (float)NROWS;
  }
}

extern "C" void kernel_launch(void* const* d_in, const int* in_sizes, int n_in,
                              void* d_out, int out_size, void* d_ws, size_t ws_size,
                              hipStream_t stream) {
  const float* X = (const float*)d_in[0];
  float* out = (float*)d_out;
  char* ws = (char*)d_ws;
  unsigned int* Xn8 = (unsigned int*)ws;
  float* density = (float*)(ws + (size_t)NROWS * KDIM);
  unsigned int* ticket = (unsigned int*)(density + NROWS);

  hipFuncSetAttribute((const void*)kde_gemm,
                      hipFuncAttributeMaxDynamicSharedMemorySize, 65536);

  kde_normalize<<<NROWS / 4, 256, 0, stream>>>(X, Xn8, density, ticket);
  kde_gemm<<<dim3(NT, NSTRIP), 256, 65536, stream>>>((const unsigned char*)ws,
                                                     density, ticket, out);
}

// Round 5
// 133.688 us; speedup vs baseline: 2.5872x; 1.0116x over previous
//
#include <hip/hip_runtime.h>

// KDE entropy loss, MI355X/gfx950 — fp8 fused GEMM, symmetric pairs once,
// wrapped-diagonal balanced mapping, A-in-registers, double-buffered B
// (1 barrier/iter), kappa*log2(e) folded into the normalize scale,
// ticketed in-kernel final reduction.
// ws: [0,4MiB) Xn fp8 [16384][256]; [4MiB,+64KiB) density f32; then ticket u32.

#define NROWS 16384
#define KDIM 256            // bytes per fp8 row
#define NTILE 128
#define NT (NROWS / NTILE)  // 128 tile rows
#define NSTRIP 4
#define TOTAL_BLOCKS (NT * NSTRIP)  // 512 = exactly 2 per CU

// sqrt(5 * log2(e)): folding into both operands scales sim by 5*log2(e),
// so kernel = exp2(sim_scaled) exactly = exp(5*sim).
#define SQRT_KLOG2E 2.68579577857f

typedef int i32x4_t __attribute__((ext_vector_type(4)));
typedef int i32x8_t __attribute__((ext_vector_type(8)));
typedef float f32x16_t __attribute__((ext_vector_type(16)));
typedef __attribute__((address_space(1))) const void global_cvoid_t;
typedef __attribute__((address_space(3))) void lds_void_t;

#if __has_builtin(__builtin_amdgcn_exp2f)
#define EXP2(x) __builtin_amdgcn_exp2f(x)
#else
#define EXP2(x) exp2f(x)
#endif

union frag8 { i32x8_t v8; i32x4_t v4[2]; };

// One wave per row: sqrt(5log2e)/max(||x||,eps), fp8 e4m3 out; zero density+ticket.
__global__ __launch_bounds__(256)
void kde_normalize(const float* __restrict__ X, unsigned int* __restrict__ Xn8,
                   float* __restrict__ density, unsigned int* __restrict__ ticket) {
  const int wave = threadIdx.x >> 6;
  const int lane = threadIdx.x & 63;
  const int row = blockIdx.x * 4 + wave;
  const float4 v = ((const float4*)(X + (size_t)row * KDIM))[lane];
  float ss = v.x * v.x + v.y * v.y + v.z * v.z + v.w * v.w;
  ss += __shfl_xor(ss, 1);
  ss += __shfl_xor(ss, 2);
  ss += __shfl_xor(ss, 4);
  ss += __shfl_xor(ss, 8);
  ss += __shfl_xor(ss, 16);
  ss += __shfl_xor(ss, 32);
  const float scale = SQRT_KLOG2E / fmaxf(sqrtf(ss), 1e-12f);
  int p = 0;
  p = __builtin_amdgcn_cvt_pk_fp8_f32(v.x * scale, v.y * scale, p, false);
  p = __builtin_amdgcn_cvt_pk_fp8_f32(v.z * scale, v.w * scale, p, true);
  Xn8[(size_t)row * 64 + lane] = (unsigned int)p;
  if (threadIdx.x < 4) density[blockIdx.x * 4 + threadIdx.x] = 0.0f;
  if (blockIdx.x == 0 && threadIdx.x == 0) *ticket = 0u;
}

// Block (bi, s): row tile bi; J-tiles (bi+t) mod 128, t in [s*16, s*16+16)
// (+ t=64 for s=3, bi<64): each unordered tile pair once. 4 waves 2x2 over
// 128x128; wave = 2x2 MFMA 32x32x64 fp8 (scale=1 -> exact e4m3 matmul).
// A fragments live in registers (loaded once); B double-buffers in 64 KB LDS
// -> 2 blocks/CU, ONE barrier per J-tile. Stage of B(k+1) issues at iter top;
// its vmcnt drain at the end barrier is a full iteration later (hidden).
__global__ __launch_bounds__(256, 2)
void kde_gemm(const unsigned char* __restrict__ Xn8, float* __restrict__ density,
              unsigned int* __restrict__ ticket, float* __restrict__ out) {
  extern __shared__ char smem[];
  char* buf0 = smem;           // 32 KB
  char* buf1 = smem + 32768;   // 32 KB

  const int tid = threadIdx.x;
  const int wave = tid >> 6;
  const int lane = tid & 63;
  const int wr = wave >> 1;
  const int wc = wave & 1;
  const int m32 = lane & 31;
  const int h = lane >> 5;
  const int bi = blockIdx.x;
  const int s = blockIdx.y;
  const int t0 = s * 16;
  const int nt = (s == NSTRIP - 1 && bi < NT / 2) ? 17 : 16;
  const char* Xb = (const char*)Xn8;

  // Chunk c = rt*8 + kb*2 + hh: lane holds M[rt*32+m32][kb*64+h*32+hh*16 ..+15].
#define STAGE(base_row, dst)                                                      \
  for (int c = wave; c < 32; c += 4) {                                            \
    const int rt = c >> 3, kb = (c >> 1) & 3, hh = c & 1;                         \
    const size_t gofs =                                                           \
        (size_t)((base_row) + rt * 32 + m32) * KDIM + kb * 64 + h * 32 + hh * 16; \
    __builtin_amdgcn_global_load_lds((global_cvoid_t*)(Xb + gofs),                \
                                     (lds_void_t*)((dst) + c * 1024), 16, 0, 0);  \
  }

  STAGE(bi * NTILE, buf0);                            // A tile -> buf0
  STAGE(((bi + t0) & (NT - 1)) * NTILE, buf1);        // B(0)   -> buf1
  __syncthreads();  // both landed (vmcnt drained at barrier)

  // A fragments -> registers (reused across all nt J-tiles).
  frag8 areg[2][4];
#pragma unroll
  for (int i = 0; i < 2; i++)
#pragma unroll
    for (int kb = 0; kb < 4; kb++) {
      const char* pa = buf0 + ((wr * 2 + i) * 8 + kb * 2) * 1024 + lane * 16;
      areg[i][kb].v4[0] = *(const i32x4_t*)pa;
      areg[i][kb].v4[1] = *(const i32x4_t*)(pa + 1024);
    }
  __syncthreads();  // all waves done reading buf0 (lgkm drained at barrier)

  float rs[2][16];
#pragma unroll
  for (int i = 0; i < 2; i++)
#pragma unroll
    for (int r = 0; r < 16; r++) rs[i][r] = 0.0f;

  for (int k = 0; k < nt; ++k) {
    const int t = t0 + k;
    const int J = (bi + t) & (NT - 1);
    char* rbuf = (k & 1) ? buf0 : buf1;  // B(k) lives here (landed at last barrier)
    char* sbuf = (k & 1) ? buf1 : buf0;  // free: all reads of it ended last barrier

    if (k + 1 < nt) STAGE(((J + 1) & (NT - 1)) * NTILE, sbuf);

    f32x16_t acc[2][2];
#pragma unroll
    for (int i = 0; i < 2; i++)
#pragma unroll
      for (int j = 0; j < 2; j++) acc[i][j] = (f32x16_t)0.0f;

#pragma unroll
    for (int kb = 0; kb < 4; ++kb) {
      frag8 bf[2];
#pragma unroll
      for (int j = 0; j < 2; j++) {
        const char* pb = rbuf + ((wc * 2 + j) * 8 + kb * 2) * 1024 + lane * 16;
        bf[j].v4[0] = *(const i32x4_t*)pb;
        bf[j].v4[1] = *(const i32x4_t*)(pb + 1024);
      }
#pragma unroll
      for (int i = 0; i < 2; i++)
#pragma unroll
        for (int j = 0; j < 2; j++)
          acc[i][j] = __builtin_amdgcn_mfma_scale_f32_32x32x64_f8f6f4(
              areg[i][kb].v8, bf[j].v8, acc[i][j], 0, 0, 0, 127, 0, 127);
    }

    // Epilogue: e = exp2(sim_scaled) = exp(5*sim). rowsums in regs across k,
    // colsums scattered now. C/D: col = m32, row = (r&3) + 8*(r>>2) + 4*h.
    float cs[2] = {0.0f, 0.0f};
#pragma unroll
    for (int i = 0; i < 2; i++)
#pragma unroll
      for (int j = 0; j < 2; j++)
#pragma unroll
        for (int r = 0; r < 16; r++) {
          const float e = EXP2(acc[i][j][r]);
          rs[i][r] += e;
          cs[j] += e;
        }

    if (t != 0) {  // diagonal tile (t=0): rowsum only
#pragma unroll
      for (int j = 0; j < 2; j++) {
        float v = cs[j] + __shfl_xor(cs[j], 32);  // combine h halves -> 64 rows
        if (h == 0)  // 2 atomics/col (wr=0,1 waves)
          atomicAdd(&density[J * NTILE + wc * 64 + j * 32 + m32], v);
      }
    }

    __syncthreads();  // B(k+1) landed; all waves done reading rbuf
  }

  // Row epilogue: reduce over 32 cols (m32) then scatter; 2 atomics/row (wc).
#pragma unroll
  for (int i = 0; i < 2; i++)
#pragma unroll
    for (int r = 0; r < 16; r++) {
      float v = rs[i][r];
      v += __shfl_xor(v, 1);
      v += __shfl_xor(v, 2);
      v += __shfl_xor(v, 4);
      v += __shfl_xor(v, 8);
      v += __shfl_xor(v, 16);
      if (m32 == 0) {
        const int row = bi * NTILE + wr * 64 + i * 32 + (r & 3) + 8 * (r >> 2) + 4 * h;
        atomicAdd(&density[row], v);
      }
    }
#undef STAGE

  // Ticket: last finished block computes the entropy (saves 2 launches).
  __syncthreads();  // all waves' atomics issued & drained (vmcnt(0) at barrier)
  if (tid == 0) {
    __threadfence();
    ((volatile unsigned int*)smem)[0] = atomicAdd(ticket, 1u);
  }
  __syncthreads();
  if (((volatile unsigned int*)smem)[0] == TOTAL_BLOCKS - 1) {
    __threadfence();
    float ssum = 0.0f;
    for (int i = tid; i < NROWS; i += 256) {
      const float d = __hip_atomic_load(&density[i], __ATOMIC_RELAXED,
                                        __HIP_MEMORY_SCOPE_AGENT);
      ssum += logf(d + 1e-9f);
    }
    ssum += __shfl_xor(ssum, 1);
    ssum += __shfl_xor(ssum, 2);
    ssum += __shfl_xor(ssum, 4);
    ssum += __shfl_xor(ssum, 8);
    ssum += __shfl_xor(ssum, 16);
    ssum += __shfl_xor(ssum, 32);
    float* red = ((float*)smem) + 16;
    if (lane == 0) red[wave] = ssum;
    __syncthreads();
    if (tid == 0) out[0] = -(red[0] + red[1] + red[2] + red[3]) / (float)NROWS;
  }
}

extern "C" void kernel_launch(void* const* d_in, const int* in_sizes, int n_in,
                              void* d_out, int out_size, void* d_ws, size_t ws_size,
                              hipStream_t stream) {
  const float* X = (const float*)d_in[0];
  float* out = (float*)d_out;
  char* ws = (char*)d_ws;
  unsigned int* Xn8 = (unsigned int*)ws;
  float* density = (float*)(ws + (size_t)NROWS * KDIM);
  unsigned int* ticket = (unsigned int*)(density + NROWS);

  hipFuncSetAttribute((const void*)kde_gemm,
                      hipFuncAttributeMaxDynamicSharedMemorySize, 65536);

  kde_normalize<<<NROWS / 4, 256, 0, stream>>>(X, Xn8, density, ticket);
  kde_gemm<<<dim3(NT, NSTRIP), 256, 65536, stream>>>((const unsigned char*)ws,
                                                     density, ticket, out);
}